// Round 7
// baseline (590.323 us; speedup 1.0000x reference)
//
#include <hip/hip_runtime.h>

namespace {

typedef unsigned short ushort_t;
typedef unsigned int uint_t;
typedef __attribute__((ext_vector_type(8))) short bf16x8;
typedef __attribute__((ext_vector_type(4))) float f32x4;

constexpr int N   = 50000;
constexpr int E   = 600000;
constexpr int NR  = 5;
constexpr int KIN = 768;
constexpr int H   = 128;
constexpr int RD  = 200;

__device__ inline ushort_t f2b(float f){           // fp32 -> bf16 bits, RNE
  uint_t u = __builtin_bit_cast(uint_t, f);
  uint_t r = (u + 0x7FFFu + ((u >> 16) & 1u)) >> 16;
  return (ushort_t)r;
}
__device__ inline float b2f_lo(uint_t u){ return __builtin_bit_cast(float, u << 16); }
__device__ inline float b2f_hi(uint_t u){ return __builtin_bit_cast(float, u & 0xFFFF0000u); }
__device__ inline float b2f_us(ushort_t h){ return __builtin_bit_cast(float, ((uint_t)h) << 16); }
__device__ inline uint_t cvtpk(float lo, float hi){ // 2x fp32 -> packed bf16 (RNE), 1 instr
  uint_t r;
  asm("v_cvt_pk_bf16_f32 %0, %1, %2" : "=v"(r) : "v"(lo), "v"(hi));
  return r;
}

// ---- prep: weight cvt (blocks 0..703) + relsc (704..705) + degcount (706..) ----
__global__ void prep_k(const float* __restrict__ l1W, const float* __restrict__ W1,
                       const float* __restrict__ R1, const float* __restrict__ W2,
                       const float* __restrict__ R2, const float* __restrict__ l2W,
                       ushort_t* __restrict__ wts, int* __restrict__ deg,
                       const int* __restrict__ edst,
                       const float* __restrict__ rel1, const float* __restrict__ Wr1,
                       const float* __restrict__ a1, float* __restrict__ sC1,
                       const float* __restrict__ rel2, const float* __restrict__ Wr2,
                       const float* __restrict__ a2, float* __restrict__ sC2){
  constexpr int S0 = H * KIN;        // 98304
  constexpr int S1 = H * H;          // 16384
  int b = blockIdx.x, tid = threadIdx.x;
  if (b < 704){                      // weight convert: 704*256 == S0 + 5*S1 exactly
    int i = b * 256 + tid;
    float v;
    if (i < S0) v = l1W[i];
    else {
      int j = i - S0, seg = j >> 14, off = j & (S1 - 1);
      const float* srcs[5] = {W1, R1, W2, R2, l2W};
      v = srcs[seg][off];
    }
    wts[i] = f2b(v);
  } else if (b < 706){               // relation scalars, one block per layer
    int L = b - 704;
    const float* rel = L ? rel2 : rel1;
    const float* Wr  = L ? Wr2  : Wr1;
    const float* a   = L ? a2   : a1;
    float*       sC  = L ? sC2  : sC1;
    __shared__ float red[256];
    int n = tid >> 1, half = tid & 1;
    float aC = a[256 + n];
    for (int r = 0; r < NR; ++r){
      float p = 0.f;
      for (int k = half * 100; k < half * 100 + 100; ++k)
        p += rel[r * RD + k] * Wr[n * RD + k];
      red[tid] = p * aC;
      __syncthreads();
      for (int s = 128; s > 0; s >>= 1){
        if (tid < s) red[tid] += red[tid + s];
        __syncthreads();
      }
      if (tid == 0) sC[r] = red[0];
      __syncthreads();
    }
  } else {                           // degree count
    int e = (b - 706) * 256 + tid;
    if (e < E) atomicAdd(&deg[edst[e]], 1);
  }
}

// ---------------- CSR build ----------------
__global__ void scan1_k(const int* __restrict__ deg, int* __restrict__ chunk,
                        int* __restrict__ bsums, int n){
  __shared__ int s[256];
  int tid = threadIdx.x, i = blockIdx.x * 256 + tid;
  int v = (i < n) ? deg[i] : 0;
  s[tid] = v; __syncthreads();
  for (int off = 1; off < 256; off <<= 1){
    int t = (tid >= off) ? s[tid - off] : 0;
    __syncthreads();
    s[tid] += t;
    __syncthreads();
  }
  if (i < n) chunk[i] = s[tid] - v;
  if (tid == 255) bsums[blockIdx.x] = s[255];
}

// scan3 with scan2 folded in: every block redundantly scans the block sums
__global__ void scan3_k(int* __restrict__ rowptr, const int* __restrict__ bsums,
                        int* __restrict__ cursor, int n, int total, int nb){
  __shared__ int s[256];
  int tid = threadIdx.x;
  int v = (tid < nb) ? bsums[tid] : 0;
  s[tid] = v; __syncthreads();
  for (int off = 1; off < 256; off <<= 1){
    int t = (tid >= off) ? s[tid - off] : 0;
    __syncthreads();
    s[tid] += t;
    __syncthreads();
  }
  int bown = (blockIdx.x < nb) ? bsums[blockIdx.x] : 0;
  int add  = s[blockIdx.x] - bown;       // exclusive prefix for this block
  int i = blockIdx.x * 256 + tid;
  if (i < n){
    int val = rowptr[i] + add;
    rowptr[i] = val; cursor[i] = val;
  }
  if (i == 0) rowptr[n] = total;
}

// fill CSR adjacency with (type<<16)|src packed (src < 65536, type < 8)
__global__ void fill_k(const int* __restrict__ src, const int* __restrict__ dst,
                       const int* __restrict__ et, int* __restrict__ cursor,
                       int* __restrict__ cpk){
  int e = blockIdx.x * 256 + threadIdx.x;
  if (e < E){
    int d = dst[e];
    int p = atomicAdd(&cursor[d], 1);
    cpk[p] = src[e] | (et[e] << 16);
  }
}

// ================= G1: h0 = leaky(x@l1W^T + b); Wx = h0@W1^T; sA/sB =================
// BK=128 -> 6 barrier rounds (round cost ~1.25us dominates; round-6 evidence).
// 64x128 tile, 4 waves; GEMM2 B staged into dead staging region; out1 written
// via coalesced Cs copy (dwordx4) instead of 64 scalar 2B stores.
__global__ __launch_bounds__(256) void g1_k(
    const float* __restrict__ Ap, const ushort_t* __restrict__ Wb1,
    const float* __restrict__ bias1, ushort_t* __restrict__ out1,
    const ushort_t* __restrict__ Wb2, const float* __restrict__ vec2,
    ushort_t* __restrict__ out2, float* __restrict__ sAo, float* __restrict__ sBo, int M)
{
  constexpr int K1 = KIN;       // 768
  constexpr int BK = 128;
  constexpr int NT = K1 / BK;   // 6
  constexpr int SP = 136;       // row stride (bf16 elems), 272 B
  __shared__ __align__(16) ushort_t U[192 * SP];   // As(64)+Bs(128) | B2s overlay; 52224 B
  __shared__ __align__(16) ushort_t Cs[64 * SP];   // 17408 B
  ushort_t* const As  = U;
  ushort_t* const Bs  = U + 64 * SP;
  ushort_t* const B2s = U;
  const int tid  = threadIdx.x;
  const int wave = tid >> 6, lane = tid & 63;
  const int l15  = lane & 15, quad = lane >> 4;
  const int row0 = blockIdx.x * 64;

  f32x4 acc[8];
  #pragma unroll
  for (int t = 0; t < 8; ++t) acc[t] = (f32x4){0.f, 0.f, 0.f, 0.f};

  // A stage: row tid>>2 (0..63), seg (tid&3)*32 elems (fp32 -> 8 float4)
  const int ar = tid >> 2, aseg = (tid & 3) * 32;
  int agrow = row0 + ar; if (agrow >= M) agrow = M - 1;
  const float* asrc = Ap + (size_t)agrow * K1 + aseg;
  // B stage: row tid>>1 (0..127), half (tid&1)*64 elems (8 uint4)
  const int bn = tid >> 1, bh = (tid & 1) * 64;
  const ushort_t* bsrc = Wb1 + (size_t)bn * K1 + bh;

  float4 pa[8]; uint4 pb[8];
#define ISSUE(kk) do{                                                           \
    _Pragma("unroll") for (int j_ = 0; j_ < 8; ++j_)                            \
      pa[j_] = *reinterpret_cast<const float4*>(asrc + (kk) + j_ * 4);          \
    _Pragma("unroll") for (int j_ = 0; j_ < 8; ++j_)                            \
      pb[j_] = *reinterpret_cast<const uint4*>(bsrc + (kk) + j_ * 8);           \
  }while(0)
#define WRITE_AB() do{                                                          \
    _Pragma("unroll") for (int j_ = 0; j_ < 4; ++j_){                           \
      uint4 av_;                                                                \
      av_.x = cvtpk(pa[2*j_].x, pa[2*j_].y);  av_.y = cvtpk(pa[2*j_].z, pa[2*j_].w); \
      av_.z = cvtpk(pa[2*j_+1].x, pa[2*j_+1].y); av_.w = cvtpk(pa[2*j_+1].z, pa[2*j_+1].w); \
      *reinterpret_cast<uint4*>(&As[ar * SP + aseg + j_ * 8]) = av_;            \
    }                                                                           \
    _Pragma("unroll") for (int j_ = 0; j_ < 8; ++j_)                            \
      *reinterpret_cast<uint4*>(&Bs[bn * SP + bh + j_ * 8]) = pb[j_];           \
  }while(0)

  ISSUE(0);
  for (int t = 0; t < NT; ++t){
    WRITE_AB();
    __syncthreads();
    if (t + 1 < NT) ISSUE((t + 1) * BK);
    #pragma unroll
    for (int kk = 0; kk < 4; ++kk){
      bf16x8 af = *reinterpret_cast<const bf16x8*>(&As[(wave * 16 + l15) * SP + kk * 32 + quad * 8]);
      #pragma unroll
      for (int tt = 0; tt < 8; ++tt){
        bf16x8 bfr = *reinterpret_cast<const bf16x8*>(&Bs[(tt * 16 + l15) * SP + kk * 32 + quad * 8]);
        acc[tt] = __builtin_amdgcn_mfma_f32_16x16x32_bf16(af, bfr, acc[tt], 0, 0, 0);
      }
    }
    __syncthreads();
  }
#undef ISSUE
#undef WRITE_AB

  // ---- B2 prefetch into regs (latency hides under epilogue VALU) ----
  uint4 wreg[8];
  #pragma unroll
  for (int i = 0; i < 8; ++i){
    int idx = tid + 256 * i;
    int rr = idx >> 4, c8 = idx & 15;
    wreg[i] = *reinterpret_cast<const uint4*>(Wb2 + (size_t)rr * 128 + c8 * 8);
  }

  // ---- epilogue 1: +bias, leaky(0.01); write Cs + B2s ----
  const int lr0 = wave * 16 + quad * 4;
  float vv[8][4];
  #pragma unroll
  for (int t = 0; t < 8; ++t){
    #pragma unroll
    for (int r = 0; r < 4; ++r){
      int col = t * 16 + l15;
      float v = acc[t][r] + bias1[col];
      vv[t][r] = v > 0.f ? v : 0.01f * v;
    }
  }
  #pragma unroll
  for (int i = 0; i < 8; ++i){
    int idx = tid + 256 * i;
    int rr = idx >> 4, c8 = idx & 15;
    *reinterpret_cast<uint4*>(&B2s[rr * SP + c8 * 8]) = wreg[i];
  }
  #pragma unroll
  for (int t = 0; t < 8; t += 2){
    #pragma unroll
    for (int r = 0; r < 4; ++r){
      int row = lr0 + r;
      int c0 = t * 16 + l15, c1 = c0 + 16;
      uint_t pr = cvtpk(vv[t][r], vv[t + 1][r]);
      Cs[row * SP + c0] = (ushort_t)pr;
      Cs[row * SP + c1] = (ushort_t)(pr >> 16);
    }
  }
  __syncthreads();

  // ---- coalesced out1 (h0) store from Cs ----
  #pragma unroll
  for (int i = 0; i < 4; ++i){
    int idx = tid + 256 * i;                // 1024 chunks of 8 bf16
    int row = idx >> 4, c8 = idx & 15;
    int g = row0 + row;
    if (g < M)
      *reinterpret_cast<uint4*>(out1 + (size_t)g * 128 + c8 * 8) =
          *reinterpret_cast<const uint4*>(&Cs[row * SP + c8 * 8]);
  }

  // ---- GEMM 2: Cs @ W2^T ----
  #pragma unroll
  for (int t = 0; t < 8; ++t) acc[t] = (f32x4){0.f, 0.f, 0.f, 0.f};
  #pragma unroll
  for (int kk = 0; kk < 4; ++kk){
    bf16x8 af2 = *reinterpret_cast<const bf16x8*>(&Cs[(wave * 16 + l15) * SP + kk * 32 + quad * 8]);
    #pragma unroll
    for (int t = 0; t < 8; ++t){
      bf16x8 bfr = *reinterpret_cast<const bf16x8*>(&B2s[(t * 16 + l15) * SP + kk * 32 + quad * 8]);
      acc[t] = __builtin_amdgcn_mfma_f32_16x16x32_bf16(af2, bfr, acc[t], 0, 0, 0);
    }
  }

  // ---- epilogue 2: bf16 Wx out + per-row sA/sB (vec2 = a) ----
  #pragma unroll
  for (int t = 0; t < 8; t += 2){
    #pragma unroll
    for (int r = 0; r < 4; ++r){
      int grow = row0 + lr0 + r;
      if (grow >= M) continue;
      int c0 = t * 16 + l15;
      uint_t pr = cvtpk(acc[t][r], acc[t + 1][r]);
      out2[(size_t)grow * 128 + c0]      = (ushort_t)pr;
      out2[(size_t)grow * 128 + c0 + 16] = (ushort_t)(pr >> 16);
    }
  }
  #pragma unroll
  for (int r = 0; r < 4; ++r){
    float pa2 = 0.f, pb2 = 0.f;
    #pragma unroll
    for (int t = 0; t < 8; ++t){
      int col = t * 16 + l15;
      pa2 += acc[t][r] * vec2[col];
      pb2 += acc[t][r] * vec2[128 + col];
    }
    #pragma unroll
    for (int off = 1; off < 16; off <<= 1){
      pa2 += __shfl_xor(pa2, off, 64);
      pb2 += __shfl_xor(pb2, off, 64);
    }
    int grow = row0 + lr0 + r;
    if (l15 == r && grow < M){ sAo[grow] = pa2; sBo[grow] = pb2; }
  }
}

// ======= G2/G3 shared impl: agg + elu(acc+agg) [+norm] ; GEMM2 ; 3 barriers =======
// K=128: B1 fully LDS-staged once; A-fragments are 4 independent per-lane global
// dwordx4 loads (each A element consumed by exactly one lane) -> NO k-loop rounds.
template<bool NORM, bool STORE1, int M2>
__device__ __forceinline__ void g23_impl(
    const ushort_t* __restrict__ Ap, const ushort_t* __restrict__ Wb1,
    const ushort_t* __restrict__ WxG, const int* __restrict__ rowptr,
    const int* __restrict__ cpk, const float* __restrict__ sAi,
    const float* __restrict__ sBi, const float* __restrict__ sCi,
    ushort_t* __restrict__ out1,
    const ushort_t* __restrict__ Wb2, const float* __restrict__ vec2,
    void* __restrict__ out2, float* __restrict__ sAo, float* __restrict__ sBo, int M)
{
  constexpr int SP = 136;
  __shared__ __align__(16) ushort_t U[128 * SP];   // B1s then B2s; 34816 B
  __shared__ __align__(16) ushort_t Cs[64 * SP];   // 17408 B
  const int tid  = threadIdx.x;
  const int wave = tid >> 6, lane = tid & 63;
  const int l15  = lane & 15, quad = lane >> 4;
  const int row0 = blockIdx.x * 64;

  // ---- direct A fragments (4 independent dwordx4 per lane) ----
  int arl = row0 + wave * 16 + l15; if (arl >= M) arl = M - 1;
  const ushort_t* arow = Ap + (size_t)arl * 128 + quad * 8;
  bf16x8 af0 = *reinterpret_cast<const bf16x8*>(arow);
  bf16x8 af1 = *reinterpret_cast<const bf16x8*>(arow + 32);
  bf16x8 af2 = *reinterpret_cast<const bf16x8*>(arow + 64);
  bf16x8 af3 = *reinterpret_cast<const bf16x8*>(arow + 96);

  // ---- stage full B1 into U ----
  {
    const int bn = tid >> 1, bh = (tid & 1) * 64;
    const ushort_t* bsrc = Wb1 + (size_t)bn * 128 + bh;
    #pragma unroll
    for (int j = 0; j < 8; ++j)
      *reinterpret_cast<uint4*>(&U[bn * SP + bh + j * 8]) =
          *reinterpret_cast<const uint4*>(bsrc + j * 8);
  }
  __syncthreads();                                  // bar 1

  // ---- GEMM 1: regs x U, no barriers ----
  f32x4 acc[8];
  #pragma unroll
  for (int t = 0; t < 8; ++t) acc[t] = (f32x4){0.f, 0.f, 0.f, 0.f};
  #pragma unroll
  for (int t = 0; t < 8; ++t){
    const ushort_t* bp = &U[(t * 16 + l15) * SP + quad * 8];
    acc[t] = __builtin_amdgcn_mfma_f32_16x16x32_bf16(af0, *reinterpret_cast<const bf16x8*>(bp),      acc[t], 0, 0, 0);
    acc[t] = __builtin_amdgcn_mfma_f32_16x16x32_bf16(af1, *reinterpret_cast<const bf16x8*>(bp + 32), acc[t], 0, 0, 0);
    acc[t] = __builtin_amdgcn_mfma_f32_16x16x32_bf16(af2, *reinterpret_cast<const bf16x8*>(bp + 64), acc[t], 0, 0, 0);
    acc[t] = __builtin_amdgcn_mfma_f32_16x16x32_bf16(af3, *reinterpret_cast<const bf16x8*>(bp + 96), acc[t], 0, 0, 0);
  }

  // ---- in-block aggregation for this block's 64 nodes -> Cs ----
  {
    const int grp = tid >> 4, l = tid & 15, gb = tid & 48;
    #pragma unroll 1
    for (int nb = 0; nb < 4; ++nb){
      int lrow = nb * 16 + grp;
      int node = row0 + lrow;
      uint4 o = make_uint4(0, 0, 0, 0);
      if (node < M){
        int p0 = rowptr[node], p1 = rowptr[node + 1];
        int dg = p1 - p0;
        float sa = sAi[node];
        float m = -1e30f, ssum = 0.f;
        float a[8];
        #pragma unroll
        for (int j = 0; j < 8; ++j) a[j] = 0.f;
        for (int c0 = 0; c0 < dg; c0 += 16){
          int cnt = dg - c0; if (cnt > 16) cnt = 16;
          bool ok = l < cnt;
          int pk = cpk[p0 + c0 + (ok ? l : 0)];
          float s = sa + sBi[pk & 0xFFFF] + sCi[pk >> 16];
          s = s > 0.f ? s : 0.2f * s;                    // leaky_relu(., 0.2)
          float sv = ok ? s : -1e30f;
          #pragma unroll
          for (int off = 8; off > 0; off >>= 1) sv = fmaxf(sv, __shfl_xor(sv, off, 16));
          float mn = fmaxf(m, sv);
          float corr = __expf(m - mn);
          ssum *= corr;
          #pragma unroll
          for (int j = 0; j < 8; ++j) a[j] *= corr;
          float ev = ok ? __expf(s - mn) : 0.f;
          float es = ev;
          #pragma unroll
          for (int off = 8; off > 0; off >>= 1) es += __shfl_xor(es, off, 16);
          ssum += es;
          m = mn;
          int png = ok ? pk : 0;
          for (int e = 0; e < cnt; e += 4){              // tails neutralized by ev=0
            int b0l = gb + e;
            int pe0 = __shfl(png, b0l,     64), pe1 = __shfl(png, b0l + 1, 64);
            int pe2 = __shfl(png, b0l + 2, 64), pe3 = __shfl(png, b0l + 3, 64);
            float e0 = __shfl(ev, b0l,     64), e1 = __shfl(ev, b0l + 1, 64);
            float e2 = __shfl(ev, b0l + 2, 64), e3 = __shfl(ev, b0l + 3, 64);
            uint4 u0 = *reinterpret_cast<const uint4*>(WxG + (size_t)(pe0 & 0xFFFF) * 128 + l * 8);
            uint4 u1 = *reinterpret_cast<const uint4*>(WxG + (size_t)(pe1 & 0xFFFF) * 128 + l * 8);
            uint4 u2 = *reinterpret_cast<const uint4*>(WxG + (size_t)(pe2 & 0xFFFF) * 128 + l * 8);
            uint4 u3 = *reinterpret_cast<const uint4*>(WxG + (size_t)(pe3 & 0xFFFF) * 128 + l * 8);
            a[0] += e0 * b2f_lo(u0.x); a[1] += e0 * b2f_hi(u0.x);
            a[2] += e0 * b2f_lo(u0.y); a[3] += e0 * b2f_hi(u0.y);
            a[4] += e0 * b2f_lo(u0.z); a[5] += e0 * b2f_hi(u0.z);
            a[6] += e0 * b2f_lo(u0.w); a[7] += e0 * b2f_hi(u0.w);
            a[0] += e1 * b2f_lo(u1.x); a[1] += e1 * b2f_hi(u1.x);
            a[2] += e1 * b2f_lo(u1.y); a[3] += e1 * b2f_hi(u1.y);
            a[4] += e1 * b2f_lo(u1.z); a[5] += e1 * b2f_hi(u1.z);
            a[6] += e1 * b2f_lo(u1.w); a[7] += e1 * b2f_hi(u1.w);
            a[0] += e2 * b2f_lo(u2.x); a[1] += e2 * b2f_hi(u2.x);
            a[2] += e2 * b2f_lo(u2.y); a[3] += e2 * b2f_hi(u2.y);
            a[4] += e2 * b2f_lo(u2.z); a[5] += e2 * b2f_hi(u2.z);
            a[6] += e2 * b2f_lo(u2.w); a[7] += e2 * b2f_hi(u2.w);
            a[0] += e3 * b2f_lo(u3.x); a[1] += e3 * b2f_hi(u3.x);
            a[2] += e3 * b2f_lo(u3.y); a[3] += e3 * b2f_hi(u3.y);
            a[4] += e3 * b2f_lo(u3.z); a[5] += e3 * b2f_hi(u3.z);
            a[6] += e3 * b2f_lo(u3.w); a[7] += e3 * b2f_hi(u3.w);
          }
        }
        float inv = (dg > 0) ? 1.f / ssum : 0.f;        // degree-0 -> zero row
        o.x = cvtpk(a[0] * inv, a[1] * inv);
        o.y = cvtpk(a[2] * inv, a[3] * inv);
        o.z = cvtpk(a[4] * inv, a[5] * inv);
        o.w = cvtpk(a[6] * inv, a[7] * inv);
      }
      *reinterpret_cast<uint4*>(&Cs[lrow * SP + l * 8]) = o;
    }
  }

  // ---- B2 prefetch into regs ----
  uint4 wreg[8];
  #pragma unroll
  for (int i = 0; i < 8; ++i){
    int idx = tid + 256 * i;
    int rr = idx >> 4, c8 = idx & 15;
    wreg[i] = *reinterpret_cast<const uint4*>(Wb2 + (size_t)rr * 128 + c8 * 8);
  }
  __syncthreads();                                  // bar 2 (agg->Cs visible; B1 reads done)

  // ---- write B2 into U (overlay) ----
  #pragma unroll
  for (int i = 0; i < 8; ++i){
    int idx = tid + 256 * i;
    int rr = idx >> 4, c8 = idx & 15;
    *reinterpret_cast<uint4*>(&U[rr * SP + c8 * 8]) = wreg[i];
  }

  // ---- epilogue 1: elu(acc + agg) [+norm], write Cs ----
  const int lr0 = wave * 16 + quad * 4;
  float vv[8][4];
  #pragma unroll
  for (int t = 0; t < 8; ++t){
    #pragma unroll
    for (int r = 0; r < 4; ++r){
      int col = t * 16 + l15;
      float v = acc[t][r] + b2f_us(Cs[(lr0 + r) * SP + col]);  // cell rewritten below by same thread
      vv[t][r] = v > 0.f ? v : __expf(v) - 1.f;
    }
  }
  if (NORM){
    #pragma unroll
    for (int r = 0; r < 4; ++r){
      float ss = 0.f;
      #pragma unroll
      for (int t = 0; t < 8; ++t) ss += vv[t][r] * vv[t][r];
      #pragma unroll
      for (int off = 1; off < 16; off <<= 1) ss += __shfl_xor(ss, off, 64);
      float sc = 1.f / fmaxf(sqrtf(ss), 1e-12f);
      #pragma unroll
      for (int t = 0; t < 8; ++t) vv[t][r] *= sc;
    }
  }
  #pragma unroll
  for (int t = 0; t < 8; t += 2){
    #pragma unroll
    for (int r = 0; r < 4; ++r){
      int row = lr0 + r;
      int c0 = t * 16 + l15, c1 = c0 + 16;
      uint_t pr = cvtpk(vv[t][r], vv[t + 1][r]);
      Cs[row * SP + c0] = (ushort_t)pr;
      Cs[row * SP + c1] = (ushort_t)(pr >> 16);
    }
  }
  __syncthreads();                                  // bar 3 (Cs result + B2s visible)

  // ---- coalesced out1 store from Cs ----
  if (STORE1){
    #pragma unroll
    for (int i = 0; i < 4; ++i){
      int idx = tid + 256 * i;
      int row = idx >> 4, c8 = idx & 15;
      int g = row0 + row;
      if (g < M)
        *reinterpret_cast<uint4*>(out1 + (size_t)g * 128 + c8 * 8) =
            *reinterpret_cast<const uint4*>(&Cs[row * SP + c8 * 8]);
    }
  }

  // ---- GEMM 2: Cs @ W2^T ----
  #pragma unroll
  for (int t = 0; t < 8; ++t) acc[t] = (f32x4){0.f, 0.f, 0.f, 0.f};
  #pragma unroll
  for (int kk = 0; kk < 4; ++kk){
    bf16x8 a2f = *reinterpret_cast<const bf16x8*>(&Cs[(wave * 16 + l15) * SP + kk * 32 + quad * 8]);
    #pragma unroll
    for (int t = 0; t < 8; ++t){
      bf16x8 bfr = *reinterpret_cast<const bf16x8*>(&U[(t * 16 + l15) * SP + kk * 32 + quad * 8]);
      acc[t] = __builtin_amdgcn_mfma_f32_16x16x32_bf16(a2f, bfr, acc[t], 0, 0, 0);
    }
  }

  // ---- epilogue 2 ----
  if (M2 == 1){
    #pragma unroll
    for (int t = 0; t < 8; ++t){
      #pragma unroll
      for (int r = 0; r < 4; ++r){
        int grow = row0 + lr0 + r;
        if (grow >= M) continue;
        int col = t * 16 + l15;
        float v = acc[t][r] + vec2[col];
        v = v > 0.f ? v : 0.01f * v;
        ((float*)out2)[(size_t)grow * 128 + col] = v;
      }
    }
  } else { // M2 == 3: bf16 out + per-row sA/sB
    #pragma unroll
    for (int t = 0; t < 8; t += 2){
      #pragma unroll
      for (int r = 0; r < 4; ++r){
        int grow = row0 + lr0 + r;
        if (grow >= M) continue;
        int c0 = t * 16 + l15;
        uint_t pr = cvtpk(acc[t][r], acc[t + 1][r]);
        ((ushort_t*)out2)[(size_t)grow * 128 + c0]      = (ushort_t)pr;
        ((ushort_t*)out2)[(size_t)grow * 128 + c0 + 16] = (ushort_t)(pr >> 16);
      }
    }
    #pragma unroll
    for (int r = 0; r < 4; ++r){
      float pa2 = 0.f, pb2 = 0.f;
      #pragma unroll
      for (int t = 0; t < 8; ++t){
        int col = t * 16 + l15;
        pa2 += acc[t][r] * vec2[col];
        pb2 += acc[t][r] * vec2[128 + col];
      }
      #pragma unroll
      for (int off = 1; off < 16; off <<= 1){
        pa2 += __shfl_xor(pa2, off, 64);
        pb2 += __shfl_xor(pb2, off, 64);
      }
      int grow = row0 + lr0 + r;
      if (l15 == r && grow < M){ sAo[grow] = pa2; sBo[grow] = pb2; }
    }
  }
}

__global__ __launch_bounds__(256) void g2_k(
    const ushort_t* Ap, const ushort_t* Wb1,
    const ushort_t* WxG, const int* rowptr, const int* cpk,
    const float* sAi, const float* sBi, const float* sCi,
    ushort_t* out1, const ushort_t* Wb2, const float* vec2,
    void* out2, float* sAo, float* sBo, int M){
  g23_impl<false, true, 3>(Ap, Wb1, WxG, rowptr, cpk, sAi, sBi, sCi,
                           out1, Wb2, vec2, out2, sAo, sBo, M);
}
__global__ __launch_bounds__(256) void g3_k(
    const ushort_t* Ap, const ushort_t* Wb1,
    const ushort_t* WxG, const int* rowptr, const int* cpk,
    const float* sAi, const float* sBi, const float* sCi,
    const ushort_t* Wb2, const float* vec2, void* out2, int M){
  g23_impl<true, false, 1>(Ap, Wb1, WxG, rowptr, cpk, sAi, sBi, sCi,
                           nullptr, Wb2, vec2, out2, nullptr, nullptr, M);
}

} // namespace

extern "C" void kernel_launch(void* const* d_in, const int* in_sizes, int n_in,
                              void* d_out, int out_size, void* d_ws, size_t ws_size,
                              hipStream_t stream)
{
  const float* x     = (const float*)d_in[0];
  const int*   eidx  = (const int*)d_in[1];
  const int*   et    = (const int*)d_in[2];
  const float* l1W   = (const float*)d_in[3];
  const float* l1b   = (const float*)d_in[4];
  const float* l2W   = (const float*)d_in[5];
  const float* l2b   = (const float*)d_in[6];
  const float* W1    = (const float*)d_in[7];
  const float* Wr1   = (const float*)d_in[8];
  const float* a1    = (const float*)d_in[9];
  const float* Wres1 = (const float*)d_in[10];
  const float* rel1  = (const float*)d_in[11];
  const float* W2    = (const float*)d_in[12];
  const float* Wr2   = (const float*)d_in[13];
  const float* a2    = (const float*)d_in[14];
  const float* Wres2 = (const float*)d_in[15];
  const float* rel2  = (const float*)d_in[16];
  float* outp = (float*)d_out;

  const int* esrc = eidx;        // edge_index[0]
  const int* edst = eidx + E;    // edge_index[1]

  // -------- workspace layout --------
  float* f = (float*)d_ws;
  size_t o = 0;
  float* sA1  = f + o; o += N;
  float* sB1  = f + o; o += N;
  float* sA2  = f + o; o += N;
  float* sB2  = f + o; o += N;
  float* sC1  = f + o; o += 8;
  float* sC2  = f + o; o += 8;
  ushort_t* us = (ushort_t*)(f + o);
  size_t ou = 0;
  ushort_t* b0   = us + ou; ou += (size_t)N * H;    // h0 bf16
  ushort_t* b1   = us + ou; ou += (size_t)N * H;    // h1 bf16
  ushort_t* WxA  = us + ou; ou += (size_t)N * H;    // Wx layer-1 bf16
  ushort_t* WxB  = us + ou; ou += (size_t)N * H;    // Wx layer-2 bf16
  ushort_t* wtsb = us + ou; ou += (size_t)H * KIN + 5 * H * H;
  ushort_t* l1Wb = wtsb;
  ushort_t* W1b  = wtsb + H * KIN;
  ushort_t* R1b  = W1b + H * H;
  ushort_t* W2b  = R1b + H * H;
  ushort_t* R2b  = W2b + H * H;
  ushort_t* l2Wb = R2b + H * H;
  if (ou & 1) ou += 1;
  int* wi = (int*)(us + ou);
  size_t oi = 0;
  int* deg    = wi + oi; oi += N;
  int* rowptr = wi + oi; oi += N + 1;
  int* cursor = wi + oi; oi += N;
  int* bsums  = wi + oi; oi += 256;
  int* boffs  = wi + oi; oi += 256;
  int* cpk    = wi + oi; oi += E;

  const int EB    = (E + 255) / 256;
  const int NB256 = (N + 255) / 256;
  const int GB    = (N + 63) / 64;

  // -------- prep (deg zero via memset; weight cvt + relsc + degcount fused) --------
  hipMemsetAsync(deg, 0, (size_t)N * sizeof(int), stream);
  prep_k<<<706 + EB, 256, 0, stream>>>(l1W, W1, Wres1, W2, Wres2, l2W, wtsb, deg,
                                       edst, rel1, Wr1, a1, sC1, rel2, Wr2, a2, sC2);
  scan1_k<<<NB256, 256, 0, stream>>>(deg, rowptr, bsums, N);
  scan3_k<<<NB256, 256, 0, stream>>>(rowptr, bsums, cursor, N, E, NB256);
  fill_k<<<EB, 256, 0, stream>>>(esrc, edst, et, cursor, cpk);

  // -------- G1: h0 = leaky(x@l1W^T+b) -> b0;  Wx1 = h0@W1^T -> WxA (+sA1/sB1) --------
  g1_k<<<GB, 256, 0, stream>>>(x, l1Wb, l1b, b0, W1b, a1, WxA, sA1, sB1, N);

  // -------- G2: agg1 (in-block); h1 = elu(agg1 + b0@R1^T) -> b1; Wx2 -> WxB --------
  g2_k<<<GB, 256, 0, stream>>>(b0, R1b, WxA, rowptr, cpk, sA1, sB1, sC1,
                               b1, W2b, a2, WxB, sA2, sB2, N);

  // -------- G3: agg2 (in-block); h2 = normalize(elu(agg2 + b1@R2^T)); out --------
  g3_k<<<GB, 256, 0, stream>>>(b1, R2b, WxB, rowptr, cpk, sA2, sB2, sC2,
                               l2Wb, l2b, outp, N);
}